// Round 9
// baseline (97.367 us; speedup 1.0000x reference)
//
#include <hip/hip_runtime.h>
#include <math.h>

#define N 8192
#define BIT 32
#define NCLASS 100
#define ALPHA 0.1
#define BEITA 1.0
#define GAMMA 0.1

#define BT 128                      // pair tile 128x128
#define NT (N / BT)                 // 64 tile-rows
#define NPAIRBLK (NT * (NT + 1) / 2)   // 2080 tiles
#define NBLK2 (NPAIRBLK / 2)        // 1040 blocks, 2 tiles each (exact)
#define NPW (NPAIRBLK * 4)          // per-wave partials: 8320
#define NPREP (N / 8)               // 1024 prep blocks, 8 rows each

// u is pre-scaled by sqrt(0.5*log2(e)) before bf16 conversion, so the MFMA
// accumulator directly yields t = log2(e) * theta. Epilogue runs in log2
// domain via softplus2(x) = log2(1+2^x):
//   pos term (sim):   softplus(th) - th = ln2 * softplus2(-t)
//   neg term (!sim):  softplus(th)      = ln2 * softplus2(+t)
// one transcendental chain on x = sim ? -t : t serves both; the single *ln2
// is folded into the finalize scale factors.
#define SCALE_BF 0.84932181f        // sqrt(0.5 * 1.4426950408889634)
#define LN2 0.6931471805599453

typedef __attribute__((ext_vector_type(8))) short s16x8;   // 8 bf16 (4 VGPRs)
typedef __attribute__((ext_vector_type(4))) float f32x4;   // MFMA accum

#if __has_builtin(__builtin_amdgcn_exp2f)
static __device__ __forceinline__ float fexp2(float x) { return __builtin_amdgcn_exp2f(x); }
#else
static __device__ __forceinline__ float fexp2(float x) { return exp2f(x); }
#endif
#if __has_builtin(__builtin_amdgcn_logf)
static __device__ __forceinline__ float flog2(float x) { return __builtin_amdgcn_logf(x); }
#else
static __device__ __forceinline__ float flog2(float x) { return __log2f(x); }
#endif

// round-to-nearest-even fp32 -> bf16 bits
static __device__ __forceinline__ unsigned short f2bf(float f) {
    unsigned int x = __float_as_uint(f);
    x += 0x7fff + ((x >> 16) & 1);
    return (unsigned short)(x >> 16);
}

// ws layout (bytes) — everything consumed is written unconditionally every call:
//   [1024..9215]      uchar lab8[N]
//   [16384..540671]   ushort ubf[N*BIT]     (bf16 of u * SCALE_BF)
//   [557056..623615]  double Ppos[8320]     (per-wave partials)
//   [630784..697343]  double Pneg[8320]
//   [704512..712703]  double Pc[1024]
//   [712704..720895]  double Pm[1024]
//   [720896..729087]  double Pb[1024]

// ---------------- prep: labels + bf16-convert u + cls + quant/bal partials ----------
__global__ __launch_bounds__(256) void prep_kernel(
    const float* __restrict__ u, const float* __restrict__ Y, const float* __restrict__ y,
    unsigned char* __restrict__ lab8, unsigned short* __restrict__ ubf,
    double* __restrict__ Pc, double* __restrict__ Pm, double* __restrict__ Pb)
{
    const int t = threadIdx.x;
    const int lane = t & 63;
    const int w = t >> 6;
    const int row0 = blockIdx.x * 8;             // block owns 8 rows

    // ---- cls + labels: wave w handles rows row0 + 2w, row0 + 2w + 1
    float wcls = 0.f;
    #pragma unroll
    for (int rr = 0; rr < 2; ++rr) {
        const int r = row0 + w * 2 + rr;
        const float* Yp = Y + (size_t)r * NCLASS;
        const float* yp = y + (size_t)r * NCLASS;
        const bool has2 = lane < (NCLASS - 64);
        float Y0 = Yp[lane];
        float Y1 = has2 ? Yp[64 + lane] : -1e30f;
        float y0 = yp[lane];
        float y1 = has2 ? yp[64 + lane] : 0.f;
        float m = fmaxf(Y0, Y1);
        #pragma unroll
        for (int o = 32; o; o >>= 1) m = fmaxf(m, __shfl_xor(m, o, 64));
        float e  = __expf(Y0 - m) + (has2 ? __expf(Y1 - m) : 0.f);
        float tg = y0 * Y0 + (has2 ? y1 * Y1 : 0.f);
        #pragma unroll
        for (int o = 32; o; o >>= 1) { e += __shfl_xor(e, o, 64); tg += __shfl_xor(tg, o, 64); }
        unsigned long long b0 = __ballot(y0 > 0.5f);
        unsigned long long b1 = __ballot(has2 && (y1 > 0.5f));
        if (lane == 0) {
            int lbl = b0 ? (__ffsll((long long)b0) - 1) : (64 + __ffsll((long long)b1) - 1);
            lab8[r] = (unsigned char)lbl;
            wcls += m + __logf(e) - tg;
        }
    }

    // ---- u: bf16 convert (pre-scaled) + quant + bal. thread t owns one float
    const size_t uidx = (size_t)row0 * BIT + t;
    const float x = u[uidx];
    ubf[uidx] = f2bf(x * SCALE_BF);
    float bb = (x > 0.f) ? 1.f : ((x < 0.f) ? -1.f : 0.f);  // jnp.sign
    float d = x - bb;
    float bal = d * d;
    float rs = x;
    #pragma unroll
    for (int o = 1; o < 32; o <<= 1) rs += __shfl_xor(rs, o, 64);  // 32 lanes = one u row
    float mrow = rs * (1.f / BIT);
    float m2 = ((t & 31) == 0) ? mrow * mrow : 0.f;
    #pragma unroll
    for (int o = 32; o; o >>= 1) { m2 += __shfl_down(m2, o, 64); bal += __shfl_down(bal, o, 64); }

    __shared__ double red[4][3];
    if (lane == 0) { red[w][0] = (double)wcls; red[w][1] = (double)m2; red[w][2] = (double)bal; }
    __syncthreads();
    if (t == 0) {
        Pc[blockIdx.x] = red[0][0] + red[1][0] + red[2][0] + red[3][0];
        Pm[blockIdx.x] = red[0][1] + red[1][1] + red[2][1] + red[3][1];
        Pb[blockIdx.x] = red[0][2] + red[1][2] + red[2][2] + red[3][2];
    }
}

// ------- pairwise hash loss: 2 tiles per block, register-pipelined ----------------
// 1040 blocks x 256 thr, tiles (b, b+1040). BOTH tiles' fragments issue up front
// (64 VGPRs); MFMA-0 waits only tile-0's loads (counted vmcnt), tile-1's loads
// land under epilogue-0 (~2000 cy) -> tile-1's load wait vanishes and per-block
// fixed costs (decode, prologue, drain) amortize over 2 tiles. Peak live ~135
// regs < 170 cap at (256,3): no spill (r7's 3-tile failure mode avoided).
// No barrier / no LDS: per-wave partial stores.
__global__ __launch_bounds__(256, 3) void pair_kernel(
    const unsigned short* __restrict__ ubf, const unsigned char* __restrict__ lab8,
    double* __restrict__ Ppos, double* __restrict__ Pneg)
{
    const int t = threadIdx.x;
    const int lane = t & 63;
    const int w = t >> 6;            // wave 0..3, 2x2 wave grid, 64x64 per wave
    const int wy = w >> 1, wx = w & 1;
    const int quad = lane >> 4, lr = lane & 15;
    const int laneoff = lr * BIT + quad * 8;   // elem offset within a 16-row stripe

    auto decode = [&](int b, int& i0, int& j0, bool& offd) {
        int ti = (int)(((float)(2 * NT + 1) - sqrtf((float)((2 * NT + 1) * (2 * NT + 1) - 8 * b))) * 0.5f);
        int S = ti * (2 * NT - ti + 1) / 2;
        if (S > b) { --ti; S = ti * (2 * NT - ti + 1) / 2; }
        else { int S2 = (ti + 1) * (2 * NT - ti) / 2; if (S2 <= b) { ++ti; S = S2; } }
        const int tj = ti + (b - S);
        i0 = ti * BT; j0 = tj * BT; offd = (ti != tj);
    };

    auto loadt = [&](int i0, int j0, s16x8 (&av)[4], s16x8 (&bv)[4],
                     int (&lavp)[4], int (&lbv)[4]) {
        const unsigned short* pa = ubf + (size_t)(i0 + wy * 64) * BIT + laneoff;
        const unsigned short* pb = ubf + (size_t)(j0 + wx * 64) * BIT + laneoff;
        #pragma unroll
        for (int x = 0; x < 4; ++x) {
            av[x] = *(const s16x8*)(pa + x * 16 * BIT);
            bv[x] = *(const s16x8*)(pb + x * 16 * BIT);
        }
        #pragma unroll
        for (int a = 0; a < 4; ++a) lavp[a] = *(const int*)(lab8 + i0 + wy * 64 + a * 16 + quad * 4);
        #pragma unroll
        for (int c = 0; c < 4; ++c) lbv[c] = (int)lab8[j0 + wx * 64 + c * 16 + lr];
    };

    auto mfmat = [&](const s16x8 (&av)[4], const s16x8 (&bv)[4], f32x4 (&acc)[4][4]) {
        #pragma unroll
        for (int a = 0; a < 4; ++a)
            #pragma unroll
            for (int c = 0; c < 4; ++c)
                acc[a][c] = __builtin_amdgcn_mfma_f32_16x16x32_bf16(
                    av[a], bv[c], (f32x4){0.f, 0.f, 0.f, 0.f}, 0, 0, 0);
    };

    // epilogue: v = softplus2(sim ? -t : t); vsum += v; vsim += v if sim.
    // Diagonal mask via runtime offd predicate, block-global coords.
    auto epit = [&](int b, bool offd, const f32x4 (&acc)[4][4],
                    const int (&lavp)[4], const int (&lbv)[4]) {
        float vsum0 = 0.f, vsum1 = 0.f, vsim0 = 0.f, vsim1 = 0.f;
        #pragma unroll
        for (int a = 0; a < 4; ++a) {
            #pragma unroll
            for (int r = 0; r < 4; ++r) {
                const int la = (lavp[a] >> (r * 8)) & 0xff;
                const int grow = wy * 64 + a * 16 + quad * 4 + r;   // block-global row
                #pragma unroll
                for (int c = 0; c < 4; ++c) {
                    const float tv = acc[a][c][r];        // = log2(e)*theta; |tv| << 127
                    const bool sim = (la == lbv[c]);
                    float x = sim ? -tv : tv;             // one cndmask w/ src modifier
                    float v = flog2(1.f + fexp2(x));      // softplus2
                    const bool keep = offd | ((wx * 64 + c * 16 + lr) > grow);
                    v = keep ? v : 0.f;
                    float vs = sim ? v : 0.f;
                    if (r & 1) { vsum1 += v; vsim1 += vs; }
                    else       { vsum0 += v; vsim0 += vs; }
                }
            }
        }
        float vsum = vsum0 + vsum1, vsim = vsim0 + vsim1;
        #pragma unroll
        for (int o = 32; o; o >>= 1) { vsum += __shfl_down(vsum, o, 64); vsim += __shfl_down(vsim, o, 64); }
        if (lane == 0) {
            Ppos[4 * b + w] = (double)vsim;               // sum_sim (softplus-theta)/ln2
            Pneg[4 * b + w] = (double)(vsum - vsim);      // sum_!sim softplus/ln2
        }
    };

    const int b0 = blockIdx.x;
    const int b1 = b0 + NBLK2;                // < 2080 always (1040*2 = 2080)

    int i0A, j0A, i0B, j0B;
    bool odA, odB;
    s16x8 avA[4], bvA[4], avB[4], bvB[4];
    int lavpA[4], lbvA[4], lavpB[4], lbvB[4];

    decode(b0, i0A, j0A, odA);
    loadt(i0A, j0A, avA, bvA, lavpA, lbvA);   // tile0 loads in flight
    decode(b1, i0B, j0B, odB);
    loadt(i0B, j0B, avB, bvB, lavpB, lbvB);   // tile1 loads in flight

    f32x4 acc[4][4];
    mfmat(avA, bvA, acc);                     // waits tile0 loads only (counted vmcnt)
    epit(b0, odA, acc, lavpA, lbvA);          // tile1 loads land under this

    mfmat(avB, bvB, acc);
    epit(b1, odB, acc, lavpB, lbvB);
}

// ---------------- finalize: histogram from labels + scales + reduce partials -----------
__global__ __launch_bounds__(256) void fin_kernel(
    const unsigned char* __restrict__ lab8, const double* __restrict__ Ppos,
    const double* __restrict__ Pneg, const double* __restrict__ Pc,
    const double* __restrict__ Pm, const double* __restrict__ Pb, float* __restrict__ out)
{
    __shared__ int h[128];
    __shared__ double red[4][5];
    __shared__ double scd[2];
    const int t = threadIdx.x;
    const int lane = t & 63;
    const int w = t >> 6;

    if (t < 128) h[t] = 0;
    __syncthreads();
    #pragma unroll
    for (int k = 0; k < 32; ++k) atomicAdd(&h[lab8[t + k * 256]], 1);
    __syncthreads();

    if (w == 0) {                 // wave 0: simsum -> scales (ln2 folded in here)
        long long c0 = (lane < NCLASS) ? h[lane] : 0;
        long long c1 = (lane + 64 < NCLASS) ? h[lane + 64] : 0;
        long long ss = c0 * c0 + c1 * c1;
        #pragma unroll
        for (int o = 32; o; o >>= 1) ss += __shfl_xor(ss, o, 64);
        if (lane == 0) {
            double s1 = (double)ss - (double)N;
            double s0 = (double)N * (double)N - (double)ss;
            if (s0 == 0.0) s0 = 1.0;
            if (s1 == 0.0) s1 = 1.0;
            double s = s0 + s1;
            scd[0] = (s / s1) * LN2;      // spos * ln2  (log2-domain partials)
            scd[1] = (s / s0) * LN2;      // sneg * ln2
        }
    }

    double p0 = 0, p1 = 0, cc = 0, mm = 0, bb = 0;
    for (int i = t; i < NPW; i += 256)   { p0 += Ppos[i]; p1 += Pneg[i]; }
    for (int i = t; i < NPREP; i += 256) { cc += Pc[i]; mm += Pm[i]; bb += Pb[i]; }
    #pragma unroll
    for (int o = 32; o; o >>= 1) {
        p0 += __shfl_down(p0, o, 64); p1 += __shfl_down(p1, o, 64);
        cc += __shfl_down(cc, o, 64); mm += __shfl_down(mm, o, 64);
        bb += __shfl_down(bb, o, 64);
    }
    if (lane == 0) { red[w][0] = p0; red[w][1] = p1; red[w][2] = cc; red[w][3] = mm; red[w][4] = bb; }
    __syncthreads();
    if (t == 0) {
        double a_pos = red[0][0] + red[1][0] + red[2][0] + red[3][0];
        double a_neg = red[0][1] + red[1][1] + red[2][1] + red[3][1];
        double a_cls = red[0][2] + red[1][2] + red[2][2] + red[3][2];
        double a_m2  = red[0][3] + red[1][3] + red[2][3] + red[3][3];
        double a_bal = red[0][4] + red[1][4] + red[2][4] + red[3][4];
        double pairsum = scd[0] * a_pos + scd[1] * a_neg;
        double lik   = 2.0 * pairsum / ((double)N * (double)(N - 1));
        double cls   = a_cls / (double)N;
        double quant = ALPHA * (a_m2 / (double)N);
        double bal   = GAMMA * (a_bal / ((double)N * (double)BIT));
        out[0] = (float)(lik + BEITA * cls + quant + bal);
    }
}

extern "C" void kernel_launch(void* const* d_in, const int* in_sizes, int n_in,
                              void* d_out, int out_size, void* d_ws, size_t ws_size,
                              hipStream_t stream) {
    const float* u = (const float*)d_in[0];   // [N, BIT]
    const float* Y = (const float*)d_in[1];   // [N, NCLASS]
    const float* y = (const float*)d_in[2];   // [N, NCLASS] one-hot
    float* out = (float*)d_out;

    char* ws = (char*)d_ws;
    unsigned char*  lab8 = (unsigned char*)(ws + 1024);
    unsigned short* ubf  = (unsigned short*)(ws + 16384);
    double* Ppos = (double*)(ws + 557056);
    double* Pneg = (double*)(ws + 630784);
    double* Pc   = (double*)(ws + 704512);
    double* Pm   = (double*)(ws + 712704);
    double* Pb   = (double*)(ws + 720896);

    prep_kernel<<<NPREP, 256, 0, stream>>>(u, Y, y, lab8, ubf, Pc, Pm, Pb);
    pair_kernel<<<NBLK2, 256, 0, stream>>>(ubf, lab8, Ppos, Pneg);
    fin_kernel<<<1, 256, 0, stream>>>(lab8, Ppos, Pneg, Pc, Pm, Pb, out);
}

// Round 10
// 88.631 us; speedup vs baseline: 1.0986x; 1.0986x over previous
//
#include <hip/hip_runtime.h>
#include <math.h>
#include <type_traits>

#define N 8192
#define BIT 32
#define NCLASS 100
#define ALPHA 0.1
#define BEITA 1.0
#define GAMMA 0.1

#define BT 128                      // pair tile 128x128
#define NT (N / BT)                 // 64 tile-rows
#define NPAIRBLK (NT * (NT + 1) / 2)   // 2080
#define NPREP (N / 8)               // 1024 prep blocks, 8 rows each

// u is pre-scaled by sqrt(0.5*log2(e)) before bf16 conversion, so the MFMA
// accumulator directly yields t = log2(e) * theta. Epilogue runs in log2
// domain via softplus2(x) = log2(1+2^x):
//   pos term (sim):   softplus(th) - th = ln2 * softplus2(-t)
//   neg term (!sim):  softplus(th)      = ln2 * softplus2(+t)
// one transcendental chain on x = sim ? -t : t serves both; the single *ln2
// is folded into the finalize scale factors.
#define SCALE_BF 0.84932181f        // sqrt(0.5 * 1.4426950408889634)
#define LN2 0.6931471805599453

typedef __attribute__((ext_vector_type(8))) short s16x8;   // 8 bf16 (4 VGPRs)
typedef __attribute__((ext_vector_type(4))) float f32x4;   // MFMA accum

#if __has_builtin(__builtin_amdgcn_exp2f)
static __device__ __forceinline__ float fexp2(float x) { return __builtin_amdgcn_exp2f(x); }
#else
static __device__ __forceinline__ float fexp2(float x) { return exp2f(x); }
#endif
#if __has_builtin(__builtin_amdgcn_logf)
static __device__ __forceinline__ float flog2(float x) { return __builtin_amdgcn_logf(x); }
#else
static __device__ __forceinline__ float flog2(float x) { return __log2f(x); }
#endif

// round-to-nearest-even fp32 -> bf16 bits
static __device__ __forceinline__ unsigned short f2bf(float f) {
    unsigned int x = __float_as_uint(f);
    x += 0x7fff + ((x >> 16) & 1);
    return (unsigned short)(x >> 16);
}

// ws layout (bytes) — everything consumed is written unconditionally every call:
//   [1024..9215]      uchar lab8[N]
//   [16384..540671]   ushort ubf[N*BIT]     (bf16 of u * SCALE_BF)
//   [557056..573695]  double Ppos[2080]
//   [630784..647423]  double Pneg[2080]
//   [704512..712703]  double Pc[1024]
//   [712704..720895]  double Pm[1024]
//   [720896..729087]  double Pb[1024]

// ---------------- prep: labels + bf16-convert u + cls + quant/bal partials ----------
__global__ __launch_bounds__(256) void prep_kernel(
    const float* __restrict__ u, const float* __restrict__ Y, const float* __restrict__ y,
    unsigned char* __restrict__ lab8, unsigned short* __restrict__ ubf,
    double* __restrict__ Pc, double* __restrict__ Pm, double* __restrict__ Pb)
{
    const int t = threadIdx.x;
    const int lane = t & 63;
    const int w = t >> 6;
    const int row0 = blockIdx.x * 8;             // block owns 8 rows

    // ---- cls + labels: wave w handles rows row0 + 2w, row0 + 2w + 1
    float wcls = 0.f;
    #pragma unroll
    for (int rr = 0; rr < 2; ++rr) {
        const int r = row0 + w * 2 + rr;
        const float* Yp = Y + (size_t)r * NCLASS;
        const float* yp = y + (size_t)r * NCLASS;
        const bool has2 = lane < (NCLASS - 64);
        float Y0 = Yp[lane];
        float Y1 = has2 ? Yp[64 + lane] : -1e30f;
        float y0 = yp[lane];
        float y1 = has2 ? yp[64 + lane] : 0.f;
        float m = fmaxf(Y0, Y1);
        #pragma unroll
        for (int o = 32; o; o >>= 1) m = fmaxf(m, __shfl_xor(m, o, 64));
        float e  = __expf(Y0 - m) + (has2 ? __expf(Y1 - m) : 0.f);
        float tg = y0 * Y0 + (has2 ? y1 * Y1 : 0.f);
        #pragma unroll
        for (int o = 32; o; o >>= 1) { e += __shfl_xor(e, o, 64); tg += __shfl_xor(tg, o, 64); }
        unsigned long long b0 = __ballot(y0 > 0.5f);
        unsigned long long b1 = __ballot(has2 && (y1 > 0.5f));
        if (lane == 0) {
            int lbl = b0 ? (__ffsll((long long)b0) - 1) : (64 + __ffsll((long long)b1) - 1);
            lab8[r] = (unsigned char)lbl;
            wcls += m + __logf(e) - tg;
        }
    }

    // ---- u: bf16 convert (pre-scaled) + quant + bal. thread t owns one float
    const size_t uidx = (size_t)row0 * BIT + t;
    const float x = u[uidx];
    ubf[uidx] = f2bf(x * SCALE_BF);
    float bb = (x > 0.f) ? 1.f : ((x < 0.f) ? -1.f : 0.f);  // jnp.sign
    float d = x - bb;
    float bal = d * d;
    float rs = x;
    #pragma unroll
    for (int o = 1; o < 32; o <<= 1) rs += __shfl_xor(rs, o, 64);  // 32 lanes = one u row
    float mrow = rs * (1.f / BIT);
    float m2 = ((t & 31) == 0) ? mrow * mrow : 0.f;
    #pragma unroll
    for (int o = 32; o; o >>= 1) { m2 += __shfl_down(m2, o, 64); bal += __shfl_down(bal, o, 64); }

    __shared__ double red[4][3];
    if (lane == 0) { red[w][0] = (double)wcls; red[w][1] = (double)m2; red[w][2] = (double)bal; }
    __syncthreads();
    if (t == 0) {
        Pc[blockIdx.x] = red[0][0] + red[1][0] + red[2][0] + red[3][0];
        Pm[blockIdx.x] = red[0][1] + red[1][1] + red[2][1] + red[3][1];
        Pb[blockIdx.x] = red[0][2] + red[1][2] + red[2][2] + red[3][2];
    }
}

// ------- pairwise hash loss: bf16 MFMA, 128x128 tiles, 256-thread blocks -----------
// Best-measured configuration (r8: 88.7 us total). 4 waves, 64x64 per wave,
// 16 MFMAs up front, minimal softplus2 epilogue. __launch_bounds__(256,3):
// 170-reg cap keeps the live set (frags 32 + acc 64 + labels + temps ~135) in
// architectural VGPRs -> no AGPR round-trips, no spill. Multi-tile pipelining
// (r7: 3-tile, r9: 2-tile) measured WORSE: a second tile's fragments + the
// accumulator exceed any usable register budget.
__global__ __launch_bounds__(256, 3) void pair_kernel(
    const unsigned short* __restrict__ ubf, const unsigned char* __restrict__ lab8,
    double* __restrict__ Ppos, double* __restrict__ Pneg)
{
    // closed-form triangular decode: b -> (ti, tj), ti <= tj
    const int b = blockIdx.x;
    int ti = (int)(((float)(2 * NT + 1) - sqrtf((float)((2 * NT + 1) * (2 * NT + 1) - 8 * b))) * 0.5f);
    int S = ti * (2 * NT - ti + 1) / 2;
    if (S > b) { --ti; S = ti * (2 * NT - ti + 1) / 2; }
    else { int S2 = (ti + 1) * (2 * NT - ti) / 2; if (S2 <= b) { ++ti; S = S2; } }
    const int tj = ti + (b - S);
    const int i0 = ti * BT, j0 = tj * BT;

    const int t = threadIdx.x;
    const int lane = t & 63;
    const int w = t >> 6;            // wave 0..3, 2x2 wave grid, 64x64 per wave
    const int wy = w >> 1, wx = w & 1;
    const int quad = lane >> 4, lr = lane & 15;
    const int ar = i0 + wy * 64;     // wave's A row base
    const int br = j0 + wx * 64;     // wave's B row base

    s16x8 av[4], bv[4];
    #pragma unroll
    for (int x = 0; x < 4; ++x) {
        av[x] = *(const s16x8*)(ubf + (size_t)(ar + x * 16 + lr) * BIT + quad * 8);
        bv[x] = *(const s16x8*)(ubf + (size_t)(br + x * 16 + lr) * BIT + quad * 8);
    }
    int lavp[4], lbv[4];
    #pragma unroll
    for (int a = 0; a < 4; ++a) lavp[a] = *(const int*)(lab8 + ar + a * 16 + quad * 4);
    #pragma unroll
    for (int c = 0; c < 4; ++c) lbv[c] = (int)lab8[br + c * 16 + lr];

    // ---- all 16 MFMAs up front: maximal ILP, one load-wait; frags die here
    f32x4 acc[4][4];
    #pragma unroll
    for (int a = 0; a < 4; ++a)
        #pragma unroll
        for (int c = 0; c < 4; ++c)
            acc[a][c] = __builtin_amdgcn_mfma_f32_16x16x32_bf16(
                av[a], bv[c], (f32x4){0.f, 0.f, 0.f, 0.f}, 0, 0, 0);

    // ---- epilogue: v = softplus2(sim ? -t : t); vsum = sum v; vsim = sum_sim v
    float vsum0 = 0.f, vsum1 = 0.f, vsim0 = 0.f, vsim1 = 0.f;
    auto run = [&](auto DIAGC) {
        constexpr bool DIAG = decltype(DIAGC)::value;
        #pragma unroll
        for (int a = 0; a < 4; ++a) {
            #pragma unroll
            for (int r = 0; r < 4; ++r) {
                const int la = (lavp[a] >> (r * 8)) & 0xff;
                const int grow = wy * 64 + a * 16 + quad * 4 + r;   // block-global row
                #pragma unroll
                for (int c = 0; c < 4; ++c) {
                    const float tv = acc[a][c][r];        // = log2(e)*theta; |tv| << 127
                    const bool sim = (la == lbv[c]);
                    float x = sim ? -tv : tv;             // one cndmask w/ src modifier
                    float v = flog2(1.f + fexp2(x));      // softplus2
                    if (DIAG) {                            // block-global strict upper
                        const bool keep = (wx * 64 + c * 16 + lr) > grow;
                        v = keep ? v : 0.f;
                    }
                    float vs = sim ? v : 0.f;
                    if (r & 1) { vsum1 += v; vsim1 += vs; }
                    else       { vsum0 += v; vsim0 += vs; }
                }
            }
        }
    };
    if (ti == tj) run(std::integral_constant<bool, true>{});
    else          run(std::integral_constant<bool, false>{});

    float vsum = vsum0 + vsum1, vsim = vsim0 + vsim1;
    #pragma unroll
    for (int o = 32; o; o >>= 1) { vsum += __shfl_down(vsum, o, 64); vsim += __shfl_down(vsim, o, 64); }
    __shared__ float wredp[4], wredn[4];
    if (lane == 0) { wredp[w] = vsim; wredn[w] = vsum - vsim; }
    __syncthreads();
    if (t == 0) {
        Ppos[b] = (double)wredp[0] + (double)wredp[1] + (double)wredp[2] + (double)wredp[3];
        Pneg[b] = (double)wredn[0] + (double)wredn[1] + (double)wredn[2] + (double)wredn[3];
    }
}

// ---------------- finalize: histogram from labels + scales + reduce partials -----------
__global__ __launch_bounds__(256) void fin_kernel(
    const unsigned char* __restrict__ lab8, const double* __restrict__ Ppos,
    const double* __restrict__ Pneg, const double* __restrict__ Pc,
    const double* __restrict__ Pm, const double* __restrict__ Pb, float* __restrict__ out)
{
    __shared__ int h[128];
    __shared__ double red[4][5];
    __shared__ double scd[2];
    const int t = threadIdx.x;
    const int lane = t & 63;
    const int w = t >> 6;

    if (t < 128) h[t] = 0;
    __syncthreads();
    #pragma unroll
    for (int k = 0; k < 32; ++k) atomicAdd(&h[lab8[t + k * 256]], 1);
    __syncthreads();

    if (w == 0) {                 // wave 0: simsum -> scales (ln2 folded in here)
        long long c0 = (lane < NCLASS) ? h[lane] : 0;
        long long c1 = (lane + 64 < NCLASS) ? h[lane + 64] : 0;
        long long ss = c0 * c0 + c1 * c1;
        #pragma unroll
        for (int o = 32; o; o >>= 1) ss += __shfl_xor(ss, o, 64);
        if (lane == 0) {
            double s1 = (double)ss - (double)N;
            double s0 = (double)N * (double)N - (double)ss;
            if (s0 == 0.0) s0 = 1.0;
            if (s1 == 0.0) s1 = 1.0;
            double s = s0 + s1;
            scd[0] = (s / s1) * LN2;      // spos * ln2  (log2-domain partials)
            scd[1] = (s / s0) * LN2;      // sneg * ln2
        }
    }

    double p0 = 0, p1 = 0, cc = 0, mm = 0, bb = 0;
    for (int i = t; i < NPAIRBLK; i += 256) { p0 += Ppos[i]; p1 += Pneg[i]; }
    for (int i = t; i < NPREP; i += 256)    { cc += Pc[i]; mm += Pm[i]; bb += Pb[i]; }
    #pragma unroll
    for (int o = 32; o; o >>= 1) {
        p0 += __shfl_down(p0, o, 64); p1 += __shfl_down(p1, o, 64);
        cc += __shfl_down(cc, o, 64); mm += __shfl_down(mm, o, 64);
        bb += __shfl_down(bb, o, 64);
    }
    if (lane == 0) { red[w][0] = p0; red[w][1] = p1; red[w][2] = cc; red[w][3] = mm; red[w][4] = bb; }
    __syncthreads();
    if (t == 0) {
        double a_pos = red[0][0] + red[1][0] + red[2][0] + red[3][0];
        double a_neg = red[0][1] + red[1][1] + red[2][1] + red[3][1];
        double a_cls = red[0][2] + red[1][2] + red[2][2] + red[3][2];
        double a_m2  = red[0][3] + red[1][3] + red[2][3] + red[3][3];
        double a_bal = red[0][4] + red[1][4] + red[2][4] + red[3][4];
        double pairsum = scd[0] * a_pos + scd[1] * a_neg;
        double lik   = 2.0 * pairsum / ((double)N * (double)(N - 1));
        double cls   = a_cls / (double)N;
        double quant = ALPHA * (a_m2 / (double)N);
        double bal   = GAMMA * (a_bal / ((double)N * (double)BIT));
        out[0] = (float)(lik + BEITA * cls + quant + bal);
    }
}

extern "C" void kernel_launch(void* const* d_in, const int* in_sizes, int n_in,
                              void* d_out, int out_size, void* d_ws, size_t ws_size,
                              hipStream_t stream) {
    const float* u = (const float*)d_in[0];   // [N, BIT]
    const float* Y = (const float*)d_in[1];   // [N, NCLASS]
    const float* y = (const float*)d_in[2];   // [N, NCLASS] one-hot
    float* out = (float*)d_out;

    char* ws = (char*)d_ws;
    unsigned char*  lab8 = (unsigned char*)(ws + 1024);
    unsigned short* ubf  = (unsigned short*)(ws + 16384);
    double* Ppos = (double*)(ws + 557056);
    double* Pneg = (double*)(ws + 630784);
    double* Pc   = (double*)(ws + 704512);
    double* Pm   = (double*)(ws + 712704);
    double* Pb   = (double*)(ws + 720896);

    prep_kernel<<<NPREP, 256, 0, stream>>>(u, Y, y, lab8, ubf, Pc, Pm, Pb);
    pair_kernel<<<NPAIRBLK, 256, 0, stream>>>(ubf, lab8, Ppos, Pneg);
    fin_kernel<<<1, 256, 0, stream>>>(lab8, Ppos, Pneg, Pc, Pm, Pb, out);
}